// Round 1
// baseline (383.585 us; speedup 1.0000x reference)
//
#include <hip/hip_runtime.h>
#include <hip/hip_bf16.h>

#define D_DIM 2048
#define E_DIM 8

typedef __attribute__((ext_vector_type(8))) short short8;
typedef __attribute__((ext_vector_type(4))) float f32x4;

__device__ __forceinline__ unsigned short f2bf(float f) {
  union { float f; unsigned int u; } v; v.f = f;
  unsigned int u = v.u;
  u += 0x7FFFu + ((u >> 16) & 1u);   // round-to-nearest-even
  return (unsigned short)(u >> 16);
}

__device__ __forceinline__ void async_copy16(const void* g, void* l) {
  __builtin_amdgcn_global_load_lds((const __attribute__((address_space(1))) void*)g,
                                   (__attribute__((address_space(3))) void*)l,
                                   16, 0, 0);
}

// ---------------- f32 -> bf16 bulk convert ----------------
__global__ void k_cvt_bf16(const float* __restrict__ in,
                           unsigned short* __restrict__ out, long long n) {
  long long i = ((long long)blockIdx.x * blockDim.x + threadIdx.x) * 8;
  const long long stride = (long long)gridDim.x * blockDim.x * 8;
  for (; i < n; i += stride) {
    float4 a = *(const float4*)(in + i);
    float4 b = *(const float4*)(in + i + 4);
    short8 r;
    r[0] = (short)f2bf(a.x); r[1] = (short)f2bf(a.y);
    r[2] = (short)f2bf(a.z); r[3] = (short)f2bf(a.w);
    r[4] = (short)f2bf(b.x); r[5] = (short)f2bf(b.y);
    r[6] = (short)f2bf(b.z); r[7] = (short)f2bf(b.w);
    *(short8*)(out + i) = r;
  }
}

// ---------------- transpose f32 -> bf16 (with zero pad) ----------------
// out[orow][oc] = (orow < in_cols ? bf16(in[oc][orow]) : 0), out ld = in_rows
__global__ void k_transpose_bf16(const float* __restrict__ in, int in_rows, int in_cols,
                                 int in_ld, unsigned short* __restrict__ out, int out_rows) {
  __shared__ float tile[32][33];
  const int tx = threadIdx.x;  // 0..31
  const int ty = threadIdx.y;  // 0..7
  const int c = blockIdx.x * 32 + tx;
  #pragma unroll
  for (int i = 0; i < 4; ++i) {
    const int r = blockIdx.y * 32 + ty + i * 8;
    float vv = 0.0f;
    if (r < in_rows && c < in_cols) vv = in[(size_t)r * in_ld + c];
    tile[ty + i * 8][tx] = vv;
  }
  __syncthreads();
  const int oc = blockIdx.y * 32 + tx;   // = original row
  #pragma unroll
  for (int i = 0; i < 4; ++i) {
    const int orow = blockIdx.x * 32 + ty + i * 8;  // = original col (padded)
    if (orow < out_rows && oc < in_rows)
      out[(size_t)orow * in_rows + oc] = f2bf(tile[tx][ty + i * 8]);
  }
}

// ---------------- pad-copy f32 -> bf16 (row-major, pad cols with 0) ----------------
__global__ void k_pad_bf16(const float* __restrict__ in, unsigned short* __restrict__ out,
                           int rows, int cols, int cols_pad) {
  long long idx = (long long)blockIdx.x * blockDim.x + threadIdx.x;
  const long long total = (long long)rows * cols_pad;
  const long long stride = (long long)gridDim.x * blockDim.x;
  for (; idx < total; idx += stride) {
    const int r = (int)(idx / cols_pad);
    const int c = (int)(idx % cols_pad);
    out[idx] = (c < cols) ? f2bf(in[(size_t)r * cols + c]) : (unsigned short)0;
  }
}

// ---------------- routing: softmax gate, coef, A2 = bf16(xu * coef / gsum) ----------------
__global__ void k_route(const float* __restrict__ xu, int k, int k_pad,
                        const float* __restrict__ Wg1, const float* __restrict__ Wg2,
                        const float* __restrict__ lam,  // [E][k]
                        unsigned short* __restrict__ A2, float* __restrict__ rowscale,
                        int Nrows) {
  const int w = threadIdx.x >> 6;
  const int lane = threadIdx.x & 63;
  const int row = blockIdx.x * 4 + w;
  if (row >= Nrows) return;
  const float* xr = xu + (size_t)row * k_pad;
  float s = 0.0f;
  for (int kk = lane; kk < k; kk += 64) s += xr[kk] * Wg1[kk];
  #pragma unroll
  for (int off = 32; off; off >>= 1) s += __shfl_xor(s, off);
  // softmax over E logits s * Wg2[e]
  float lg[E_DIM];
  float mx = -INFINITY;
  #pragma unroll
  for (int e = 0; e < E_DIM; ++e) { lg[e] = s * Wg2[e]; mx = fmaxf(mx, lg[e]); }
  float Z = 0.0f;
  #pragma unroll
  for (int e = 0; e < E_DIM; ++e) { lg[e] = expf(lg[e] - mx); Z += lg[e]; }
  float g[E_DIM]; float gsum = 0.0f;
  #pragma unroll
  for (int e = 0; e < E_DIM; ++e) { g[e] = lg[e] / Z; gsum += g[e]; }
  const float inv = 1.0f / gsum;
  if (lane == 0) rowscale[row] = gsum;
  unsigned short* arow = A2 + (size_t)row * k_pad;
  for (int kk = lane; kk < k_pad; kk += 64) {
    if (kk < k) {
      float c = 0.0f;
      #pragma unroll
      for (int e = 0; e < E_DIM; ++e) c += g[e] * lam[(size_t)e * k + kk];
      arow[kk] = f2bf(xr[kk] * (c * inv));
    } else {
      arow[kk] = 0;
    }
  }
}

// ---------------- bf16 MFMA GEMM, K split across two segments ----------------
// C[M x Nn] = Acat[M x Ktot] @ Bcat[Ktot x Nn], B given transposed (Bt[n][kk]).
// Segment 0: first ka0 k-cols from A0/B0; rest from A1/B1.
// EPI==0: plain f32 store.  EPI==1: val *= rowscale[row] * (1 + vcol[col]).
template<int EPI>
__global__ __launch_bounds__(256, 2) void k_gemm(
    const unsigned short* __restrict__ A0, int lda0,
    const unsigned short* __restrict__ A1, int lda1,
    const unsigned short* __restrict__ B0, int ldb0,
    const unsigned short* __restrict__ B1, int ldb1,
    int ka0, int Ktot,
    float* __restrict__ Cout, int ldc,
    const float* __restrict__ rowscale, const float* __restrict__ vcol) {
  __shared__ unsigned short As[128 * 32];
  __shared__ unsigned short Bs[128 * 32];
  const int tid = threadIdx.x;
  const int lane = tid & 63;
  const int w = tid >> 6;
  const int brow = blockIdx.x * 128;
  const int bcol = blockIdx.y * 128;

  f32x4 acc[4][4];
  #pragma unroll
  for (int m = 0; m < 4; ++m)
    #pragma unroll
    for (int n2 = 0; n2 < 4; ++n2)
      #pragma unroll
      for (int j = 0; j < 4; ++j) acc[m][n2][j] = 0.0f;

  const int srow = lane >> 2;        // 0..15 (row within 16-row chunk)
  const int scol = (lane & 3) * 8;   // element col within 32-wide K tile
  const int wr = (w >> 1) * 64;
  const int wc = (w & 1) * 64;
  const int nkt = Ktot >> 5;

  for (int kt = 0; kt < nkt; ++kt) {
    const int k0 = kt * 32;
    const unsigned short* Ab; int ldA; int kA;
    const unsigned short* Bb; int ldB; int kB;
    if (k0 < ka0) { Ab = A0; ldA = lda0; kA = k0;       Bb = B0; ldB = ldb0; kB = k0; }
    else          { Ab = A1; ldA = lda1; kA = k0 - ka0; Bb = B1; ldB = ldb1; kB = k0 - ka0; }
    __syncthreads();   // previous tile fully consumed
    #pragma unroll
    for (int p = 0; p < 2; ++p) {
      const int c = p * 4 + w;             // chunk 0..7, wave-uniform
      const int row = c * 16 + srow;
      async_copy16(Ab + (size_t)(brow + row) * ldA + kA + scol, (void*)(As + c * 512));
      async_copy16(Bb + (size_t)(bcol + row) * ldB + kB + scol, (void*)(Bs + c * 512));
    }
    __syncthreads();   // staging complete (compiler drains vmcnt before barrier)
    short8 av[4], bv[4];
    #pragma unroll
    for (int m = 0; m < 4; ++m)
      av[m] = *(const short8*)(As + (wr + m * 16 + (lane & 15)) * 32 + (lane >> 4) * 8);
    #pragma unroll
    for (int n2 = 0; n2 < 4; ++n2)
      bv[n2] = *(const short8*)(Bs + (wc + n2 * 16 + (lane & 15)) * 32 + (lane >> 4) * 8);
    #pragma unroll
    for (int m = 0; m < 4; ++m)
      #pragma unroll
      for (int n2 = 0; n2 < 4; ++n2)
        acc[m][n2] = __builtin_amdgcn_mfma_f32_16x16x32_bf16(av[m], bv[n2], acc[m][n2], 0, 0, 0);
  }

  // epilogue: C/D layout col = lane&15, row = (lane>>4)*4 + j  [m89-verified]
  #pragma unroll
  for (int m = 0; m < 4; ++m) {
    #pragma unroll
    for (int n2 = 0; n2 < 4; ++n2) {
      const int col = bcol + wc + n2 * 16 + (lane & 15);
      float cs = 1.0f;
      if (EPI == 1) cs = 1.0f + vcol[col];
      #pragma unroll
      for (int j = 0; j < 4; ++j) {
        const int row = brow + wr + m * 16 + (lane >> 4) * 4 + j;
        float val = acc[m][n2][j];
        if (EPI == 1) val *= rowscale[row] * cs;
        Cout[(size_t)row * ldc + col] = val;
      }
    }
  }
}

extern "C" void kernel_launch(void* const* d_in, const int* in_sizes, int n_in,
                              void* d_out, int out_size, void* d_ws, size_t ws_size,
                              hipStream_t stream) {
  const float* x   = (const float*)d_in[0];
  const float* W   = (const float*)d_in[1];
  const float* U   = (const float*)d_in[2];
  const float* V   = (const float*)d_in[3];
  const float* lam = (const float*)d_in[4];
  const float* v   = (const float*)d_in[5];
  const float* Wg1 = (const float*)d_in[6];
  const float* Wg2 = (const float*)d_in[7];
  float* out = (float*)d_out;

  const int N = in_sizes[0] / D_DIM;        // 16384
  const int k = in_sizes[2] / D_DIM;        // SVD rank (~566)
  const int k_pad = (k + 127) & ~127;       // multiple of 128

  char* ws = (char*)d_ws;
  size_t off = 0;
  auto alloc = [&](size_t bytes) -> void* {
    void* p = ws + off;
    off += (bytes + 255) & ~(size_t)255;
    return p;
  };
  unsigned short* xb  = (unsigned short*)alloc((size_t)N * D_DIM * 2);     // x bf16
  unsigned short* Wt  = (unsigned short*)alloc((size_t)D_DIM * D_DIM * 2); // W^T bf16
  unsigned short* Ukt = (unsigned short*)alloc((size_t)k_pad * D_DIM * 2); // U^T bf16 (padded)
  unsigned short* Vb  = (unsigned short*)alloc((size_t)D_DIM * k_pad * 2); // V bf16 (padded)
  float*          xu  = (float*)alloc((size_t)N * k_pad * 4);              // x@U f32
  unsigned short* A2  = (unsigned short*)alloc((size_t)N * k_pad * 2);     // (xu*coef) bf16
  float*          rs  = (float*)alloc((size_t)N * 4);                      // per-row gsum
  if (off > ws_size) return;  // insufficient workspace -> fail visibly, no corruption

  // 1) conversions
  k_cvt_bf16<<<2048, 256, 0, stream>>>(x, xb, (long long)N * D_DIM);
  k_transpose_bf16<<<dim3(D_DIM / 32, D_DIM / 32), dim3(32, 8), 0, stream>>>(
      W, D_DIM, D_DIM, D_DIM, Wt, D_DIM);
  k_transpose_bf16<<<dim3(k_pad / 32, D_DIM / 32), dim3(32, 8), 0, stream>>>(
      U, D_DIM, k, k, Ukt, k_pad);
  k_pad_bf16<<<512, 256, 0, stream>>>(V, Vb, D_DIM, k, k_pad);

  // 2) xu = x @ U_k   [N, k_pad] f32
  k_gemm<0><<<dim3(N / 128, k_pad / 128), 256, 0, stream>>>(
      xb, D_DIM, nullptr, 0,
      Ukt, D_DIM, nullptr, 0,
      D_DIM, D_DIM,
      xu, k_pad, nullptr, nullptr);

  // 3) routing -> A2, rowscale
  k_route<<<N / 4, 256, 0, stream>>>(xu, k, k_pad, Wg1, Wg2, lam, A2, rs, N);

  // 4) fused GEMM: out = (x@W + A2@V^T) * rowscale * (1+v)
  k_gemm<1><<<dim3(N / 128, D_DIM / 128), 256, 0, stream>>>(
      xb, D_DIM, A2, k_pad,
      Wt, D_DIM, Vb, k_pad,
      D_DIM, D_DIM + k_pad,
      out, D_DIM, rs, v);
}

// Round 2
// 348.922 us; speedup vs baseline: 1.0993x; 1.0993x over previous
//
#include <hip/hip_runtime.h>
#include <hip/hip_bf16.h>

#define D_DIM 2048
#define E_DIM 8

typedef __attribute__((ext_vector_type(8))) short short8;
typedef __attribute__((ext_vector_type(4))) float f32x4;

__device__ __forceinline__ unsigned short f2bf(float f) {
  union { float f; unsigned int u; } v; v.f = f;
  unsigned int u = v.u;
  u += 0x7FFFu + ((u >> 16) & 1u);   // round-to-nearest-even
  return (unsigned short)(u >> 16);
}

__device__ __forceinline__ void async_copy16(const void* g, void* l) {
  __builtin_amdgcn_global_load_lds((const __attribute__((address_space(1))) void*)g,
                                   (__attribute__((address_space(3))) void*)l,
                                   16, 0, 0);
}

// ---------------- f32 -> bf16 bulk convert ----------------
__global__ void k_cvt_bf16(const float* __restrict__ in,
                           unsigned short* __restrict__ out, long long n) {
  long long i = ((long long)blockIdx.x * blockDim.x + threadIdx.x) * 8;
  const long long stride = (long long)gridDim.x * blockDim.x * 8;
  for (; i < n; i += stride) {
    float4 a = *(const float4*)(in + i);
    float4 b = *(const float4*)(in + i + 4);
    short8 r;
    r[0] = (short)f2bf(a.x); r[1] = (short)f2bf(a.y);
    r[2] = (short)f2bf(a.z); r[3] = (short)f2bf(a.w);
    r[4] = (short)f2bf(b.x); r[5] = (short)f2bf(b.y);
    r[6] = (short)f2bf(b.z); r[7] = (short)f2bf(b.w);
    *(short8*)(out + i) = r;
  }
}

// ---------------- transpose f32 -> bf16 (with zero pad) ----------------
__global__ void k_transpose_bf16(const float* __restrict__ in, int in_rows, int in_cols,
                                 int in_ld, unsigned short* __restrict__ out, int out_rows) {
  __shared__ float tile[32][33];
  const int tx = threadIdx.x;  // 0..31
  const int ty = threadIdx.y;  // 0..7
  const int c = blockIdx.x * 32 + tx;
  #pragma unroll
  for (int i = 0; i < 4; ++i) {
    const int r = blockIdx.y * 32 + ty + i * 8;
    float vv = 0.0f;
    if (r < in_rows && c < in_cols) vv = in[(size_t)r * in_ld + c];
    tile[ty + i * 8][tx] = vv;
  }
  __syncthreads();
  const int oc = blockIdx.y * 32 + tx;   // = original row
  #pragma unroll
  for (int i = 0; i < 4; ++i) {
    const int orow = blockIdx.x * 32 + ty + i * 8;  // = original col (padded)
    if (orow < out_rows && oc < in_rows)
      out[(size_t)orow * in_rows + oc] = f2bf(tile[tx][ty + i * 8]);
  }
}

// ---------------- pad-copy f32 -> bf16 (row-major, pad cols with 0) ----------------
__global__ void k_pad_bf16(const float* __restrict__ in, unsigned short* __restrict__ out,
                           int rows, int cols, int cols_pad) {
  long long idx = (long long)blockIdx.x * blockDim.x + threadIdx.x;
  const long long total = (long long)rows * cols_pad;
  const long long stride = (long long)gridDim.x * blockDim.x;
  for (; idx < total; idx += stride) {
    const int r = (int)(idx / cols_pad);
    const int c = (int)(idx % cols_pad);
    out[idx] = (c < cols) ? f2bf(in[(size_t)r * cols + c]) : (unsigned short)0;
  }
}

// ---------------- routing ----------------
__global__ void k_route(const float* __restrict__ xu, int k, int k_pad,
                        const float* __restrict__ Wg1, const float* __restrict__ Wg2,
                        const float* __restrict__ lam,  // [E][k]
                        unsigned short* __restrict__ A2, float* __restrict__ rowscale,
                        int Nrows) {
  const int w = threadIdx.x >> 6;
  const int lane = threadIdx.x & 63;
  const int row = blockIdx.x * 4 + w;
  if (row >= Nrows) return;
  const float* xr = xu + (size_t)row * k_pad;
  float s = 0.0f;
  for (int kk = lane; kk < k; kk += 64) s += xr[kk] * Wg1[kk];
  #pragma unroll
  for (int off = 32; off; off >>= 1) s += __shfl_xor(s, off);
  float lg[E_DIM];
  float mx = -INFINITY;
  #pragma unroll
  for (int e = 0; e < E_DIM; ++e) { lg[e] = s * Wg2[e]; mx = fmaxf(mx, lg[e]); }
  float Z = 0.0f;
  #pragma unroll
  for (int e = 0; e < E_DIM; ++e) { lg[e] = expf(lg[e] - mx); Z += lg[e]; }
  float g[E_DIM]; float gsum = 0.0f;
  #pragma unroll
  for (int e = 0; e < E_DIM; ++e) { g[e] = lg[e] / Z; gsum += g[e]; }
  const float inv = 1.0f / gsum;
  if (lane == 0) rowscale[row] = gsum;
  unsigned short* arow = A2 + (size_t)row * k_pad;
  for (int kk = lane; kk < k_pad; kk += 64) {
    if (kk < k) {
      float c = 0.0f;
      #pragma unroll
      for (int e = 0; e < E_DIM; ++e) c += g[e] * lam[(size_t)e * k + kk];
      arow[kk] = f2bf(xr[kk] * (c * inv));
    } else {
      arow[kk] = 0;
    }
  }
}

// ---------------- 128x128 2-phase GEMM (kept for the narrow xu GEMM) ----------------
template<int EPI>
__global__ __launch_bounds__(256, 2) void k_gemm(
    const unsigned short* __restrict__ A0, int lda0,
    const unsigned short* __restrict__ A1, int lda1,
    const unsigned short* __restrict__ B0, int ldb0,
    const unsigned short* __restrict__ B1, int ldb1,
    int ka0, int Ktot,
    float* __restrict__ Cout, int ldc,
    const float* __restrict__ rowscale, const float* __restrict__ vcol) {
  __shared__ unsigned short As[128 * 32];
  __shared__ unsigned short Bs[128 * 32];
  const int tid = threadIdx.x;
  const int lane = tid & 63;
  const int w = tid >> 6;
  const int brow = blockIdx.x * 128;
  const int bcol = blockIdx.y * 128;

  f32x4 acc[4][4];
  #pragma unroll
  for (int m = 0; m < 4; ++m)
    #pragma unroll
    for (int n2 = 0; n2 < 4; ++n2)
      #pragma unroll
      for (int j = 0; j < 4; ++j) acc[m][n2][j] = 0.0f;

  const int srow = lane >> 2;
  const int scol = (lane & 3) * 8;
  const int wr = (w >> 1) * 64;
  const int wc = (w & 1) * 64;
  const int nkt = Ktot >> 5;

  for (int kt = 0; kt < nkt; ++kt) {
    const int k0 = kt * 32;
    const unsigned short* Ab; int ldA; int kA;
    const unsigned short* Bb; int ldB; int kB;
    if (k0 < ka0) { Ab = A0; ldA = lda0; kA = k0;       Bb = B0; ldB = ldb0; kB = k0; }
    else          { Ab = A1; ldA = lda1; kA = k0 - ka0; Bb = B1; ldB = ldb1; kB = k0 - ka0; }
    __syncthreads();
    #pragma unroll
    for (int p = 0; p < 2; ++p) {
      const int c = p * 4 + w;
      const int row = c * 16 + srow;
      async_copy16(Ab + (size_t)(brow + row) * ldA + kA + scol, (void*)(As + c * 512));
      async_copy16(Bb + (size_t)(bcol + row) * ldB + kB + scol, (void*)(Bs + c * 512));
    }
    __syncthreads();
    short8 av[4], bv[4];
    #pragma unroll
    for (int m = 0; m < 4; ++m)
      av[m] = *(const short8*)(As + (wr + m * 16 + (lane & 15)) * 32 + (lane >> 4) * 8);
    #pragma unroll
    for (int n2 = 0; n2 < 4; ++n2)
      bv[n2] = *(const short8*)(Bs + (wc + n2 * 16 + (lane & 15)) * 32 + (lane >> 4) * 8);
    #pragma unroll
    for (int m = 0; m < 4; ++m)
      #pragma unroll
      for (int n2 = 0; n2 < 4; ++n2)
        acc[m][n2] = __builtin_amdgcn_mfma_f32_16x16x32_bf16(av[m], bv[n2], acc[m][n2], 0, 0, 0);
  }

  #pragma unroll
  for (int m = 0; m < 4; ++m) {
    #pragma unroll
    for (int n2 = 0; n2 < 4; ++n2) {
      const int col = bcol + wc + n2 * 16 + (lane & 15);
      float cs = 1.0f;
      if (EPI == 1) cs = 1.0f + vcol[col];
      #pragma unroll
      for (int j = 0; j < 4; ++j) {
        const int row = brow + wr + m * 16 + (lane >> 4) * 4 + j;
        float val = acc[m][n2][j];
        if (EPI == 1) val *= rowscale[row] * cs;
        Cout[(size_t)row * ldc + col] = val;
      }
    }
  }
}

// ---------------- 256x256 8-wave phase-split GEMM with counted vmcnt ----------------
// Tile 256x256, BK=32, 4 LDS slots (4-tile rotation, 3-tile prefetch depth).
// Per K-tile: 2 phases x 16 MFMA; stage one future half (A then B) per phase.
// LDS slot s: A-region [256][32] bf16 (16KB) + B-region [256][32] (16KB).
// XOR swizzle: 16B-slot j at row r stored at j ^ ((r>>1)&3), applied on the
// GLOBAL source of global_load_lds (linear LDS dest) and on ds_read.
template<int EPI>
__global__ __launch_bounds__(512, 2) void k_gemm256(
    const unsigned short* __restrict__ A0, int lda0,
    const unsigned short* __restrict__ A1, int lda1,
    const unsigned short* __restrict__ B0, int ldb0,
    const unsigned short* __restrict__ B1, int ldb1,
    int ka0, int Ktot, int gridM,
    float* __restrict__ Cout, int ldc,
    const float* __restrict__ rowscale, const float* __restrict__ vcol) {
  __shared__ unsigned short lds[4 * 16384];   // 128 KiB
  const int tid = threadIdx.x;
  const int lane = tid & 63;
  const int w = tid >> 6;            // 0..7
  const int wm = w >> 2;             // 0..1  (M half)
  const int wn = w & 3;              // 0..3  (N quarter)

  // bijective XCD swizzle (grid size divisible by 8)
  int bid = blockIdx.x;
  const int cpx = gridDim.x >> 3;
  bid = (bid & 7) * cpx + (bid >> 3);
  const int bx = bid % gridM;
  const int by = bid / gridM;
  const long long brow = (long long)bx * 256;
  const long long bcol = (long long)by * 256;

  // staging geometry: 16 chunks of 1KB per region; wave w owns chunks 2w, 2w+1
  const int c0 = w * 2;
  const int sr0 = lane >> 2;         // row within 16-row chunk
  const int sj  = lane & 3;          // 16B slot within 64B row

  auto stage = [&](int tt, const unsigned short* P, long long ldP, int kbase,
                   long long rbase, int breg) {
    unsigned short* dst = lds + (tt & 3) * 16384 + breg * 8192;
    #pragma unroll
    for (int c = 0; c < 2; ++c) {
      const int chunk = c0 + c;
      const int lrow = chunk * 16 + sr0;
      const int jj = sj ^ ((lrow >> 1) & 3);
      const unsigned short* src = P + (rbase + lrow) * ldP + kbase + jj * 8;
      async_copy16(src, (void*)(dst + chunk * 512));
    }
  };

  const int NT = Ktot >> 5;

  auto segA = [&](int tt, const unsigned short*& P, long long& ld, int& kb) {
    const int k0 = tt * 32;
    if (k0 < ka0) { P = A0; ld = lda0; kb = k0; }
    else          { P = A1; ld = lda1; kb = k0 - ka0; }
  };
  auto segB = [&](int tt, const unsigned short*& P, long long& ld, int& kb) {
    const int k0 = tt * 32;
    if (k0 < ka0) { P = B0; ld = ldb0; kb = k0; }
    else          { P = B1; ld = ldb1; kb = k0 - ka0; }
  };

  // prologue: stage tiles 0..2
  for (int p = 0; p < 3; ++p) {
    const unsigned short* PA; long long ldA; int kA; segA(p, PA, ldA, kA);
    const unsigned short* PB; long long ldB; int kB; segB(p, PB, ldB, kB);
    stage(p, PA, ldA, kA, brow, 0);
    stage(p, PB, ldB, kB, bcol, 1);
  }
  asm volatile("s_waitcnt vmcnt(8)" ::: "memory");   // tile 0 landed
  __builtin_amdgcn_s_barrier();

  f32x4 acc[8][4];
  #pragma unroll
  for (int m = 0; m < 8; ++m)
    #pragma unroll
    for (int n = 0; n < 4; ++n)
      #pragma unroll
      for (int j = 0; j < 4; ++j) acc[m][n][j] = 0.0f;

  const int l15 = lane & 15;
  const int jhi = lane >> 4;

  for (int t = 0; t < NT; ++t) {
    const unsigned short* Areg = lds + (t & 3) * 16384;
    const unsigned short* Breg = Areg + 8192;
    short8 av[8], bv[2];

    // ---------- phase A: A-frags + B cols [0,32), stage A of tile t+3 ----------
    #pragma unroll
    for (int m = 0; m < 8; ++m) {
      const int row = wm * 128 + m * 16 + l15;
      const int jj = jhi ^ ((row >> 1) & 3);
      av[m] = *(const short8*)(Areg + row * 32 + jj * 8);
    }
    #pragma unroll
    for (int n = 0; n < 2; ++n) {
      const int row = wn * 64 + n * 16 + l15;
      const int jj = jhi ^ ((row >> 1) & 3);
      bv[n] = *(const short8*)(Breg + row * 32 + jj * 8);
    }
    if (t + 3 < NT) {
      const unsigned short* PA; long long ldA; int kA; segA(t + 3, PA, ldA, kA);
      stage(t + 3, PA, ldA, kA, brow, 0);
    }
    __builtin_amdgcn_s_barrier();
    __builtin_amdgcn_s_setprio(1);
    #pragma unroll
    for (int m = 0; m < 8; ++m)
      #pragma unroll
      for (int n = 0; n < 2; ++n)
        acc[m][n] = __builtin_amdgcn_mfma_f32_16x16x32_bf16(av[m], bv[n], acc[m][n], 0, 0, 0);
    __builtin_amdgcn_s_setprio(0);
    __builtin_amdgcn_s_barrier();

    // ---------- phase B: B cols [32,64), stage B of tile t+3 ----------
    #pragma unroll
    for (int n = 0; n < 2; ++n) {
      const int row = wn * 64 + 32 + n * 16 + l15;
      const int jj = jhi ^ ((row >> 1) & 3);
      bv[n] = *(const short8*)(Breg + row * 32 + jj * 8);
    }
    if (t + 3 < NT) {
      const unsigned short* PB; long long ldB; int kB; segB(t + 3, PB, ldB, kB);
      stage(t + 3, PB, ldB, kB, bcol, 1);
    }
    __builtin_amdgcn_s_barrier();
    __builtin_amdgcn_s_setprio(1);
    #pragma unroll
    for (int m = 0; m < 8; ++m)
      #pragma unroll
      for (int n = 0; n < 2; ++n)
        acc[m][2 + n] = __builtin_amdgcn_mfma_f32_16x16x32_bf16(av[m], bv[n], acc[m][2 + n], 0, 0, 0);
    __builtin_amdgcn_s_setprio(0);
    // counted drain: keep 2 tiles (8 loads) in flight; tail peels 8 -> 4 -> 0
    if (t + 3 < NT)      asm volatile("s_waitcnt vmcnt(8)" ::: "memory");
    else if (t + 2 < NT) asm volatile("s_waitcnt vmcnt(4)" ::: "memory");
    else if (t + 1 < NT) asm volatile("s_waitcnt vmcnt(0)" ::: "memory");
    __builtin_amdgcn_s_barrier();
  }

  // epilogue: C/D layout col = lane&15, row = (lane>>4)*4 + j
  #pragma unroll
  for (int m = 0; m < 8; ++m) {
    #pragma unroll
    for (int n = 0; n < 4; ++n) {
      const long long col = bcol + wn * 64 + n * 16 + l15;
      float cs = 1.0f;
      if (EPI == 1) cs = 1.0f + vcol[col];
      #pragma unroll
      for (int j = 0; j < 4; ++j) {
        const long long row = brow + wm * 128 + m * 16 + jhi * 4 + j;
        float val = acc[m][n][j];
        if (EPI == 1) val *= rowscale[row] * cs;
        Cout[row * ldc + col] = val;
      }
    }
  }
}

extern "C" void kernel_launch(void* const* d_in, const int* in_sizes, int n_in,
                              void* d_out, int out_size, void* d_ws, size_t ws_size,
                              hipStream_t stream) {
  const float* x   = (const float*)d_in[0];
  const float* W   = (const float*)d_in[1];
  const float* U   = (const float*)d_in[2];
  const float* V   = (const float*)d_in[3];
  const float* lam = (const float*)d_in[4];
  const float* v   = (const float*)d_in[5];
  const float* Wg1 = (const float*)d_in[6];
  const float* Wg2 = (const float*)d_in[7];
  float* out = (float*)d_out;

  const int N = in_sizes[0] / D_DIM;        // 16384
  const int k = in_sizes[2] / D_DIM;        // SVD rank (~566)
  const int k_pad = (k + 127) & ~127;       // multiple of 128

  char* ws = (char*)d_ws;
  size_t off = 0;
  auto alloc = [&](size_t bytes) -> void* {
    void* p = ws + off;
    off += (bytes + 255) & ~(size_t)255;
    return p;
  };
  unsigned short* xb  = (unsigned short*)alloc((size_t)N * D_DIM * 2);
  unsigned short* Wt  = (unsigned short*)alloc((size_t)D_DIM * D_DIM * 2);
  unsigned short* Ukt = (unsigned short*)alloc((size_t)k_pad * D_DIM * 2);
  unsigned short* Vb  = (unsigned short*)alloc((size_t)D_DIM * k_pad * 2);
  float*          xu  = (float*)alloc((size_t)N * k_pad * 4);
  unsigned short* A2  = (unsigned short*)alloc((size_t)N * k_pad * 2);
  float*          rs  = (float*)alloc((size_t)N * 4);
  if (off > ws_size) return;

  // 1) conversions
  k_cvt_bf16<<<2048, 256, 0, stream>>>(x, xb, (long long)N * D_DIM);
  k_transpose_bf16<<<dim3(D_DIM / 32, D_DIM / 32), dim3(32, 8), 0, stream>>>(
      W, D_DIM, D_DIM, D_DIM, Wt, D_DIM);
  k_transpose_bf16<<<dim3(k_pad / 32, D_DIM / 32), dim3(32, 8), 0, stream>>>(
      U, D_DIM, k, k, Ukt, k_pad);
  k_pad_bf16<<<512, 256, 0, stream>>>(V, Vb, D_DIM, k, k_pad);

  // 2) xu = x @ U_k   [N, k_pad] f32   (narrow N -> keep 128^2 kernel)
  k_gemm<0><<<dim3(N / 128, k_pad / 128), 256, 0, stream>>>(
      xb, D_DIM, nullptr, 0,
      Ukt, D_DIM, nullptr, 0,
      D_DIM, D_DIM,
      xu, k_pad, nullptr, nullptr);

  // 3) routing -> A2, rowscale
  k_route<<<N / 4, 256, 0, stream>>>(xu, k, k_pad, Wg1, Wg2, lam, A2, rs, N);

  // 4) fused GEMM: out = (x@W + A2@V^T) * rowscale * (1+v)  [256^2 8-wave]
  const int gridM = N / 256;                 // 64
  const int gridN = D_DIM / 256;             // 8
  k_gemm256<1><<<gridM * gridN, 512, 0, stream>>>(
      xb, D_DIM, A2, k_pad,
      Wt, D_DIM, Vb, k_pad,
      D_DIM, D_DIM + k_pad, gridM,
      out, D_DIM, rs, v);
}

// Round 3
// 347.528 us; speedup vs baseline: 1.1038x; 1.0040x over previous
//
#include <hip/hip_runtime.h>
#include <hip/hip_bf16.h>

#define D_DIM 2048
#define E_DIM 8

typedef __attribute__((ext_vector_type(8))) short short8;
typedef __attribute__((ext_vector_type(4))) float f32x4;

__device__ __forceinline__ unsigned short f2bf(float f) {
  union { float f; unsigned int u; } v; v.f = f;
  unsigned int u = v.u;
  u += 0x7FFFu + ((u >> 16) & 1u);   // round-to-nearest-even
  return (unsigned short)(u >> 16);
}

__device__ __forceinline__ void async_copy16(const void* g, void* l) {
  __builtin_amdgcn_global_load_lds((const __attribute__((address_space(1))) void*)g,
                                   (__attribute__((address_space(3))) void*)l,
                                   16, 0, 0);
}

// ---------------- f32 -> bf16 bulk convert ----------------
__global__ void k_cvt_bf16(const float* __restrict__ in,
                           unsigned short* __restrict__ out, long long n) {
  long long i = ((long long)blockIdx.x * blockDim.x + threadIdx.x) * 8;
  const long long stride = (long long)gridDim.x * blockDim.x * 8;
  for (; i < n; i += stride) {
    float4 a = *(const float4*)(in + i);
    float4 b = *(const float4*)(in + i + 4);
    short8 r;
    r[0] = (short)f2bf(a.x); r[1] = (short)f2bf(a.y);
    r[2] = (short)f2bf(a.z); r[3] = (short)f2bf(a.w);
    r[4] = (short)f2bf(b.x); r[5] = (short)f2bf(b.y);
    r[6] = (short)f2bf(b.z); r[7] = (short)f2bf(b.w);
    *(short8*)(out + i) = r;
  }
}

// ---------------- transpose f32 -> bf16 (with zero pad) ----------------
__global__ void k_transpose_bf16(const float* __restrict__ in, int in_rows, int in_cols,
                                 int in_ld, unsigned short* __restrict__ out, int out_rows) {
  __shared__ float tile[32][33];
  const int tx = threadIdx.x;  // 0..31
  const int ty = threadIdx.y;  // 0..7
  const int c = blockIdx.x * 32 + tx;
  #pragma unroll
  for (int i = 0; i < 4; ++i) {
    const int r = blockIdx.y * 32 + ty + i * 8;
    float vv = 0.0f;
    if (r < in_rows && c < in_cols) vv = in[(size_t)r * in_ld + c];
    tile[ty + i * 8][tx] = vv;
  }
  __syncthreads();
  const int oc = blockIdx.y * 32 + tx;   // = original row
  #pragma unroll
  for (int i = 0; i < 4; ++i) {
    const int orow = blockIdx.x * 32 + ty + i * 8;  // = original col (padded)
    if (orow < out_rows && oc < in_rows)
      out[(size_t)orow * in_rows + oc] = f2bf(tile[tx][ty + i * 8]);
  }
}

// ---------------- pad-copy f32 -> bf16 (row-major, pad cols with 0) ----------------
__global__ void k_pad_bf16(const float* __restrict__ in, unsigned short* __restrict__ out,
                           int rows, int cols, int cols_pad) {
  long long idx = (long long)blockIdx.x * blockDim.x + threadIdx.x;
  const long long total = (long long)rows * cols_pad;
  const long long stride = (long long)gridDim.x * blockDim.x;
  for (; idx < total; idx += stride) {
    const int r = (int)(idx / cols_pad);
    const int c = (int)(idx % cols_pad);
    out[idx] = (c < cols) ? f2bf(in[(size_t)r * cols + c]) : (unsigned short)0;
  }
}

// ---------------- routing ----------------
__global__ void k_route(const float* __restrict__ xu, int k, int k_pad,
                        const float* __restrict__ Wg1, const float* __restrict__ Wg2,
                        const float* __restrict__ lam,  // [E][k]
                        unsigned short* __restrict__ A2, float* __restrict__ rowscale,
                        int Nrows) {
  const int w = threadIdx.x >> 6;
  const int lane = threadIdx.x & 63;
  const int row = blockIdx.x * 4 + w;
  if (row >= Nrows) return;
  const float* xr = xu + (size_t)row * k_pad;
  float s = 0.0f;
  for (int kk = lane; kk < k; kk += 64) s += xr[kk] * Wg1[kk];
  #pragma unroll
  for (int off = 32; off; off >>= 1) s += __shfl_xor(s, off);
  float lg[E_DIM];
  float mx = -INFINITY;
  #pragma unroll
  for (int e = 0; e < E_DIM; ++e) { lg[e] = s * Wg2[e]; mx = fmaxf(mx, lg[e]); }
  float Z = 0.0f;
  #pragma unroll
  for (int e = 0; e < E_DIM; ++e) { lg[e] = expf(lg[e] - mx); Z += lg[e]; }
  float g[E_DIM]; float gsum = 0.0f;
  #pragma unroll
  for (int e = 0; e < E_DIM; ++e) { g[e] = lg[e] / Z; gsum += g[e]; }
  const float inv = 1.0f / gsum;
  if (lane == 0) rowscale[row] = gsum;
  unsigned short* arow = A2 + (size_t)row * k_pad;
  for (int kk = lane; kk < k_pad; kk += 64) {
    if (kk < k) {
      float c = 0.0f;
      #pragma unroll
      for (int e = 0; e < E_DIM; ++e) c += g[e] * lam[(size_t)e * k + kk];
      arow[kk] = f2bf(xr[kk] * (c * inv));
    } else {
      arow[kk] = 0;
    }
  }
}

// ---------------- 128x128 4-wave, 4-slot rotation, counted vmcnt, 1 barrier/K-tile ----
// Used for xu = x @ U_k (single K segment). Swizzle: 16B slot j of row r stored
// at j ^ ((r>>1)&3); applied to global SOURCE (linear LDS dest) and on ds_read.
__global__ __launch_bounds__(256, 2) void k_gemm128(
    const unsigned short* __restrict__ A, long long lda,
    const unsigned short* __restrict__ B, long long ldb,
    int Ktot, float* __restrict__ Cout, int ldc) {
  __shared__ unsigned short lds[4 * 8192];   // 64 KiB: slot = A[128][32] + B[128][32]
  const int tid = threadIdx.x;
  const int lane = tid & 63;
  const int w = tid >> 6;            // 0..3
  const long long brow = (long long)blockIdx.x * 128;
  const long long bcol = (long long)blockIdx.y * 128;
  const int c0 = w * 2;
  const int sr0 = lane >> 2;
  const int sj  = lane & 3;

  auto stage = [&](int tt, const unsigned short* P, long long ldP, long long rbase, int breg) {
    unsigned short* dst = lds + (tt & 3) * 8192 + breg * 4096;
    #pragma unroll
    for (int c = 0; c < 2; ++c) {
      const int chunk = c0 + c;
      const int lrow = chunk * 16 + sr0;
      const int jj = sj ^ ((lrow >> 1) & 3);
      async_copy16(P + (rbase + lrow) * ldP + (long long)tt * 32 + jj * 8,
                   (void*)(dst + chunk * 512));
    }
  };

  const int NT = Ktot >> 5;
  for (int p = 0; p < 3; ++p) { stage(p, A, lda, brow, 0); stage(p, B, ldb, bcol, 1); }
  asm volatile("s_waitcnt vmcnt(8)" ::: "memory");
  __builtin_amdgcn_s_barrier();

  f32x4 acc[4][4];
  #pragma unroll
  for (int m = 0; m < 4; ++m)
    #pragma unroll
    for (int n = 0; n < 4; ++n)
      #pragma unroll
      for (int j = 0; j < 4; ++j) acc[m][n][j] = 0.0f;

  const int l15 = lane & 15;
  const int jhi = lane >> 4;
  const int wr = (w >> 1) * 64;
  const int wc = (w & 1) * 64;

  for (int t = 0; t < NT; ++t) {
    const unsigned short* Areg = lds + (t & 3) * 8192;
    const unsigned short* Breg = Areg + 4096;
    if (t + 3 < NT) { stage(t + 3, A, lda, brow, 0); stage(t + 3, B, ldb, bcol, 1); }
    short8 av[4], bv[4];
    #pragma unroll
    for (int m = 0; m < 4; ++m) {
      const int row = wr + m * 16 + l15;
      const int jj = jhi ^ ((row >> 1) & 3);
      av[m] = *(const short8*)(Areg + row * 32 + jj * 8);
    }
    #pragma unroll
    for (int n = 0; n < 4; ++n) {
      const int row = wc + n * 16 + l15;
      const int jj = jhi ^ ((row >> 1) & 3);
      bv[n] = *(const short8*)(Breg + row * 32 + jj * 8);
    }
    __builtin_amdgcn_s_setprio(1);
    #pragma unroll
    for (int m = 0; m < 4; ++m)
      #pragma unroll
      for (int n = 0; n < 4; ++n)
        acc[m][n] = __builtin_amdgcn_mfma_f32_16x16x32_bf16(av[m], bv[n], acc[m][n], 0, 0, 0);
    __builtin_amdgcn_s_setprio(0);
    if (t + 3 < NT)      asm volatile("s_waitcnt vmcnt(8)" ::: "memory");
    else if (t + 2 < NT) asm volatile("s_waitcnt vmcnt(4)" ::: "memory");
    else if (t + 1 < NT) asm volatile("s_waitcnt vmcnt(0)" ::: "memory");
    __builtin_amdgcn_s_barrier();
  }

  #pragma unroll
  for (int m = 0; m < 4; ++m) {
    #pragma unroll
    for (int n = 0; n < 4; ++n) {
      const long long col = bcol + wc + n * 16 + l15;
      #pragma unroll
      for (int j = 0; j < 4; ++j) {
        const long long row = brow + wr + m * 16 + jhi * 4 + j;
        Cout[row * ldc + col] = acc[m][n][j];
      }
    }
  }
}

// ---------------- 256x256 8-wave, 4-slot rotation, counted vmcnt, 1 barrier/K-tile ----
// K split across two segments (A0/B0 then A1/B1). EPI: *rowscale[row]*(1+vcol[col]).
template<int EPI>
__global__ __launch_bounds__(512, 2) void k_gemm256(
    const unsigned short* __restrict__ A0, int lda0,
    const unsigned short* __restrict__ A1, int lda1,
    const unsigned short* __restrict__ B0, int ldb0,
    const unsigned short* __restrict__ B1, int ldb1,
    int ka0, int Ktot, int gridM,
    float* __restrict__ Cout, int ldc,
    const float* __restrict__ rowscale, const float* __restrict__ vcol) {
  __shared__ unsigned short lds[4 * 16384];   // 128 KiB
  const int tid = threadIdx.x;
  const int lane = tid & 63;
  const int w = tid >> 6;            // 0..7
  const int wm = w >> 2;             // 0..1  (M half)
  const int wn = w & 3;              // 0..3  (N quarter)

  // bijective XCD swizzle (grid size divisible by 8)
  int bid = blockIdx.x;
  const int cpx = gridDim.x >> 3;
  bid = (bid & 7) * cpx + (bid >> 3);
  const int bx = bid % gridM;
  const int by = bid / gridM;
  const long long brow = (long long)bx * 256;
  const long long bcol = (long long)by * 256;

  const int c0 = w * 2;
  const int sr0 = lane >> 2;
  const int sj  = lane & 3;

  auto stage = [&](int tt, const unsigned short* P, long long ldP, int kbase,
                   long long rbase, int breg) {
    unsigned short* dst = lds + (tt & 3) * 16384 + breg * 8192;
    #pragma unroll
    for (int c = 0; c < 2; ++c) {
      const int chunk = c0 + c;
      const int lrow = chunk * 16 + sr0;
      const int jj = sj ^ ((lrow >> 1) & 3);
      const unsigned short* src = P + (rbase + lrow) * ldP + kbase + jj * 8;
      async_copy16(src, (void*)(dst + chunk * 512));
    }
  };

  const int NT = Ktot >> 5;

  auto segA = [&](int tt, const unsigned short*& P, long long& ld, int& kb) {
    const int k0 = tt * 32;
    if (k0 < ka0) { P = A0; ld = lda0; kb = k0; }
    else          { P = A1; ld = lda1; kb = k0 - ka0; }
  };
  auto segB = [&](int tt, const unsigned short*& P, long long& ld, int& kb) {
    const int k0 = tt * 32;
    if (k0 < ka0) { P = B0; ld = ldb0; kb = k0; }
    else          { P = B1; ld = ldb1; kb = k0 - ka0; }
  };

  // prologue: stage tiles 0..2
  for (int p = 0; p < 3; ++p) {
    const unsigned short* PA; long long ldA; int kA; segA(p, PA, ldA, kA);
    const unsigned short* PB; long long ldB; int kB; segB(p, PB, ldB, kB);
    stage(p, PA, ldA, kA, brow, 0);
    stage(p, PB, ldB, kB, bcol, 1);
  }
  asm volatile("s_waitcnt vmcnt(8)" ::: "memory");   // tile 0 landed
  __builtin_amdgcn_s_barrier();

  f32x4 acc[8][4];
  #pragma unroll
  for (int m = 0; m < 8; ++m)
    #pragma unroll
    for (int n = 0; n < 4; ++n)
      #pragma unroll
      for (int j = 0; j < 4; ++j) acc[m][n][j] = 0.0f;

  const int l15 = lane & 15;
  const int jhi = lane >> 4;

  for (int t = 0; t < NT; ++t) {
    const unsigned short* Areg = lds + (t & 3) * 16384;
    const unsigned short* Breg = Areg + 8192;

    // stage tile t+3 (A and B) — lands in slot (t+3)&3, read slot is t&3
    if (t + 3 < NT) {
      const unsigned short* PA; long long ldA; int kA; segA(t + 3, PA, ldA, kA);
      stage(t + 3, PA, ldA, kA, brow, 0);
      const unsigned short* PB; long long ldB; int kB; segB(t + 3, PB, ldB, kB);
      stage(t + 3, PB, ldB, kB, bcol, 1);
    }

    // fragments for this K-tile (compiler interleaves lgkmcnt with MFMA issue)
    short8 av[8], bv[4];
    #pragma unroll
    for (int m = 0; m < 8; ++m) {
      const int row = wm * 128 + m * 16 + l15;
      const int jj = jhi ^ ((row >> 1) & 3);
      av[m] = *(const short8*)(Areg + row * 32 + jj * 8);
    }
    #pragma unroll
    for (int n = 0; n < 4; ++n) {
      const int row = wn * 64 + n * 16 + l15;
      const int jj = jhi ^ ((row >> 1) & 3);
      bv[n] = *(const short8*)(Breg + row * 32 + jj * 8);
    }

    __builtin_amdgcn_s_setprio(1);
    #pragma unroll
    for (int m = 0; m < 8; ++m)
      #pragma unroll
      for (int n = 0; n < 4; ++n)
        acc[m][n] = __builtin_amdgcn_mfma_f32_16x16x32_bf16(av[m], bv[n], acc[m][n], 0, 0, 0);
    __builtin_amdgcn_s_setprio(0);

    // counted drain: keep 2 tiles (8 loads) in flight; tail peels 8 -> 4 -> 0
    if (t + 3 < NT)      asm volatile("s_waitcnt vmcnt(8)" ::: "memory");
    else if (t + 2 < NT) asm volatile("s_waitcnt vmcnt(4)" ::: "memory");
    else if (t + 1 < NT) asm volatile("s_waitcnt vmcnt(0)" ::: "memory");
    __builtin_amdgcn_s_barrier();
  }

  // epilogue: C/D layout col = lane&15, row = (lane>>4)*4 + j
  #pragma unroll
  for (int m = 0; m < 8; ++m) {
    #pragma unroll
    for (int n = 0; n < 4; ++n) {
      const long long col = bcol + wn * 64 + n * 16 + l15;
      float cs = 1.0f;
      if (EPI == 1) cs = 1.0f + vcol[col];
      #pragma unroll
      for (int j = 0; j < 4; ++j) {
        const long long row = brow + wm * 128 + m * 16 + jhi * 4 + j;
        float val = acc[m][n][j];
        if (EPI == 1) val *= rowscale[row] * cs;
        Cout[row * ldc + col] = val;
      }
    }
  }
}

extern "C" void kernel_launch(void* const* d_in, const int* in_sizes, int n_in,
                              void* d_out, int out_size, void* d_ws, size_t ws_size,
                              hipStream_t stream) {
  const float* x   = (const float*)d_in[0];
  const float* W   = (const float*)d_in[1];
  const float* U   = (const float*)d_in[2];
  const float* V   = (const float*)d_in[3];
  const float* lam = (const float*)d_in[4];
  const float* v   = (const float*)d_in[5];
  const float* Wg1 = (const float*)d_in[6];
  const float* Wg2 = (const float*)d_in[7];
  float* out = (float*)d_out;

  const int N = in_sizes[0] / D_DIM;        // 16384
  const int k = in_sizes[2] / D_DIM;        // SVD rank (~566)
  const int k_pad = (k + 127) & ~127;       // multiple of 128

  char* ws = (char*)d_ws;
  size_t off = 0;
  auto alloc = [&](size_t bytes) -> void* {
    void* p = ws + off;
    off += (bytes + 255) & ~(size_t)255;
    return p;
  };
  unsigned short* xb  = (unsigned short*)alloc((size_t)N * D_DIM * 2);
  unsigned short* Wt  = (unsigned short*)alloc((size_t)D_DIM * D_DIM * 2);
  unsigned short* Ukt = (unsigned short*)alloc((size_t)k_pad * D_DIM * 2);
  unsigned short* Vb  = (unsigned short*)alloc((size_t)D_DIM * k_pad * 2);
  float*          xu  = (float*)alloc((size_t)N * k_pad * 4);
  unsigned short* A2  = (unsigned short*)alloc((size_t)N * k_pad * 2);
  float*          rs  = (float*)alloc((size_t)N * 4);
  if (off > ws_size) return;

  // 1) conversions
  k_cvt_bf16<<<2048, 256, 0, stream>>>(x, xb, (long long)N * D_DIM);
  k_transpose_bf16<<<dim3(D_DIM / 32, D_DIM / 32), dim3(32, 8), 0, stream>>>(
      W, D_DIM, D_DIM, D_DIM, Wt, D_DIM);
  k_transpose_bf16<<<dim3(k_pad / 32, D_DIM / 32), dim3(32, 8), 0, stream>>>(
      U, D_DIM, k, k, Ukt, k_pad);
  k_pad_bf16<<<512, 256, 0, stream>>>(V, Vb, D_DIM, k, k_pad);

  // 2) xu = x @ U_k   [N, k_pad] f32
  k_gemm128<<<dim3(N / 128, k_pad / 128), 256, 0, stream>>>(
      xb, D_DIM, Ukt, D_DIM, D_DIM, xu, k_pad);

  // 3) routing -> A2, rowscale
  k_route<<<N / 4, 256, 0, stream>>>(xu, k, k_pad, Wg1, Wg2, lam, A2, rs, N);

  // 4) fused GEMM: out = (x@W + A2@V^T) * rowscale * (1+v)  [256^2 8-wave]
  const int gridM = N / 256;                 // 64
  const int gridN = D_DIM / 256;             // 8
  k_gemm256<1><<<gridM * gridN, 512, 0, stream>>>(
      xb, D_DIM, A2, k_pad,
      Wt, D_DIM, Vb, k_pad,
      D_DIM, D_DIM + k_pad, gridM,
      out, D_DIM, rs, v);
}

// Round 4
// 344.424 us; speedup vs baseline: 1.1137x; 1.0090x over previous
//
#include <hip/hip_runtime.h>
#include <hip/hip_bf16.h>

#define D_DIM 2048
#define E_DIM 8

typedef __attribute__((ext_vector_type(8))) short short8;
typedef __attribute__((ext_vector_type(4))) float f32x4;

__device__ __forceinline__ unsigned short f2bf(float f) {
  union { float f; unsigned int u; } v; v.f = f;
  unsigned int u = v.u;
  u += 0x7FFFu + ((u >> 16) & 1u);   // round-to-nearest-even
  return (unsigned short)(u >> 16);
}

__device__ __forceinline__ void async_copy16(const void* g, void* l) {
  __builtin_amdgcn_global_load_lds((const __attribute__((address_space(1))) void*)g,
                                   (__attribute__((address_space(3))) void*)l,
                                   16, 0, 0);
}

// ---------------- f32 -> bf16 bulk convert ----------------
__global__ void k_cvt_bf16(const float* __restrict__ in,
                           unsigned short* __restrict__ out, long long n) {
  long long i = ((long long)blockIdx.x * blockDim.x + threadIdx.x) * 8;
  const long long stride = (long long)gridDim.x * blockDim.x * 8;
  for (; i < n; i += stride) {
    float4 a = *(const float4*)(in + i);
    float4 b = *(const float4*)(in + i + 4);
    short8 r;
    r[0] = (short)f2bf(a.x); r[1] = (short)f2bf(a.y);
    r[2] = (short)f2bf(a.z); r[3] = (short)f2bf(a.w);
    r[4] = (short)f2bf(b.x); r[5] = (short)f2bf(b.y);
    r[6] = (short)f2bf(b.z); r[7] = (short)f2bf(b.w);
    *(short8*)(out + i) = r;
  }
}

// ---------------- transpose f32 -> bf16 (with zero pad) ----------------
__global__ void k_transpose_bf16(const float* __restrict__ in, int in_rows, int in_cols,
                                 int in_ld, unsigned short* __restrict__ out, int out_rows) {
  __shared__ float tile[32][33];
  const int tx = threadIdx.x;  // 0..31
  const int ty = threadIdx.y;  // 0..7
  const int c = blockIdx.x * 32 + tx;
  #pragma unroll
  for (int i = 0; i < 4; ++i) {
    const int r = blockIdx.y * 32 + ty + i * 8;
    float vv = 0.0f;
    if (r < in_rows && c < in_cols) vv = in[(size_t)r * in_ld + c];
    tile[ty + i * 8][tx] = vv;
  }
  __syncthreads();
  const int oc = blockIdx.y * 32 + tx;   // = original row
  #pragma unroll
  for (int i = 0; i < 4; ++i) {
    const int orow = blockIdx.x * 32 + ty + i * 8;  // = original col (padded)
    if (orow < out_rows && oc < in_rows)
      out[(size_t)orow * in_rows + oc] = f2bf(tile[tx][ty + i * 8]);
  }
}

// ---------------- pad-copy f32 -> bf16 (row-major, pad cols with 0) ----------------
__global__ void k_pad_bf16(const float* __restrict__ in, unsigned short* __restrict__ out,
                           int rows, int cols, int cols_pad) {
  long long idx = (long long)blockIdx.x * blockDim.x + threadIdx.x;
  const long long total = (long long)rows * cols_pad;
  const long long stride = (long long)gridDim.x * blockDim.x;
  for (; idx < total; idx += stride) {
    const int r = (int)(idx / cols_pad);
    const int c = (int)(idx % cols_pad);
    out[idx] = (c < cols) ? f2bf(in[(size_t)r * cols + c]) : (unsigned short)0;
  }
}

// ---------------- routing ----------------
__global__ void k_route(const float* __restrict__ xu, int k, int k_pad,
                        const float* __restrict__ Wg1, const float* __restrict__ Wg2,
                        const float* __restrict__ lam,  // [E][k]
                        unsigned short* __restrict__ A2, float* __restrict__ rowscale,
                        int Nrows) {
  const int w = threadIdx.x >> 6;
  const int lane = threadIdx.x & 63;
  const int row = blockIdx.x * 4 + w;
  if (row >= Nrows) return;
  const float* xr = xu + (size_t)row * k_pad;
  float s = 0.0f;
  for (int kk = lane; kk < k; kk += 64) s += xr[kk] * Wg1[kk];
  #pragma unroll
  for (int off = 32; off; off >>= 1) s += __shfl_xor(s, off);
  float lg[E_DIM];
  float mx = -INFINITY;
  #pragma unroll
  for (int e = 0; e < E_DIM; ++e) { lg[e] = s * Wg2[e]; mx = fmaxf(mx, lg[e]); }
  float Z = 0.0f;
  #pragma unroll
  for (int e = 0; e < E_DIM; ++e) { lg[e] = expf(lg[e] - mx); Z += lg[e]; }
  float g[E_DIM]; float gsum = 0.0f;
  #pragma unroll
  for (int e = 0; e < E_DIM; ++e) { g[e] = lg[e] / Z; gsum += g[e]; }
  const float inv = 1.0f / gsum;
  if (lane == 0) rowscale[row] = gsum;
  unsigned short* arow = A2 + (size_t)row * k_pad;
  for (int kk = lane; kk < k_pad; kk += 64) {
    if (kk < k) {
      float c = 0.0f;
      #pragma unroll
      for (int e = 0; e < E_DIM; ++e) c += g[e] * lam[(size_t)e * k + kk];
      arow[kk] = f2bf(xr[kk] * (c * inv));
    } else {
      arow[kk] = 0;
    }
  }
}

// ---------------- 128x128 4-wave, 4-slot rotation, reg-double-buffered frags ----------
// Body t: stage(t+3); ds_read frags of tile t+1 (alt reg set); MFMA tile t;
// vmcnt(4) (=> tile t+2 landed for next body's read-ahead); barrier.
__global__ __launch_bounds__(256, 2) void k_gemm128(
    const unsigned short* __restrict__ A, long long lda,
    const unsigned short* __restrict__ B, long long ldb,
    int Ktot, float* __restrict__ Cout, int ldc) {
  __shared__ unsigned short lds[4 * 8192];   // 64 KiB: slot = A[128][32] + B[128][32]
  const int tid = threadIdx.x;
  const int lane = tid & 63;
  const int w = tid >> 6;            // 0..3
  const long long brow = (long long)blockIdx.x * 128;
  const long long bcol = (long long)blockIdx.y * 128;
  const int c0 = w * 2;
  const int sr0 = lane >> 2;
  const int sj  = lane & 3;
  const int l15 = lane & 15;
  const int jhi = lane >> 4;
  const int wr = (w >> 1) * 64;
  const int wc = (w & 1) * 64;

  auto stage = [&](int tt) {
    unsigned short* dstA = lds + (tt & 3) * 8192;
    #pragma unroll
    for (int c = 0; c < 2; ++c) {
      const int chunk = c0 + c;
      const int lrow = chunk * 16 + sr0;
      const int jj = sj ^ ((lrow >> 1) & 3);
      async_copy16(A + (brow + lrow) * lda + (long long)tt * 32 + jj * 8,
                   (void*)(dstA + chunk * 512));
      async_copy16(B + (bcol + lrow) * ldb + (long long)tt * 32 + jj * 8,
                   (void*)(dstA + 4096 + chunk * 512));
    }
  };

  auto load_frags = [&](int tt, short8* av, short8* bv) {
    const unsigned short* Areg = lds + (tt & 3) * 8192;
    const unsigned short* Breg = Areg + 4096;
    #pragma unroll
    for (int m = 0; m < 4; ++m) {
      const int row = wr + m * 16 + l15;
      const int jj = jhi ^ ((row >> 1) & 3);
      av[m] = *(const short8*)(Areg + row * 32 + jj * 8);
    }
    #pragma unroll
    for (int n = 0; n < 4; ++n) {
      const int row = wc + n * 16 + l15;
      const int jj = jhi ^ ((row >> 1) & 3);
      bv[n] = *(const short8*)(Breg + row * 32 + jj * 8);
    }
  };

  f32x4 acc[4][4];
  #pragma unroll
  for (int m = 0; m < 4; ++m)
    #pragma unroll
    for (int n = 0; n < 4; ++n)
      #pragma unroll
      for (int j = 0; j < 4; ++j) acc[m][n][j] = 0.0f;

  auto do_mfma = [&](short8* av, short8* bv) {
    __builtin_amdgcn_s_setprio(1);
    #pragma unroll
    for (int m = 0; m < 4; ++m)
      #pragma unroll
      for (int n = 0; n < 4; ++n)
        acc[m][n] = __builtin_amdgcn_mfma_f32_16x16x32_bf16(av[m], bv[n], acc[m][n], 0, 0, 0);
    __builtin_amdgcn_s_setprio(0);
  };

  const int NT = Ktot >> 5;   // even (K multiple of 64)
  stage(0); stage(1); stage(2);
  asm volatile("s_waitcnt vmcnt(4)" ::: "memory");   // tiles 0,1 landed
  __builtin_amdgcn_s_barrier();

  short8 avA[4], bvA[4], avB[4], bvB[4];
  load_frags(0, avA, bvA);

  for (int t = 0; t < NT; t += 2) {
    // body t: compute set A, read t+1 into set B
    if (t + 3 < NT) stage(t + 3);
    load_frags(t + 1, avB, bvB);          // t+1 < NT always (NT even)
    do_mfma(avA, bvA);
    asm volatile("s_waitcnt vmcnt(4)" ::: "memory");
    __builtin_amdgcn_s_barrier();
    // body t+1: compute set B, read t+2 into set A
    if (t + 4 < NT) stage(t + 4);
    if (t + 2 < NT) load_frags(t + 2, avA, bvA);
    do_mfma(avB, bvB);
    asm volatile("s_waitcnt vmcnt(4)" ::: "memory");
    __builtin_amdgcn_s_barrier();
  }

  #pragma unroll
  for (int m = 0; m < 4; ++m) {
    #pragma unroll
    for (int n = 0; n < 4; ++n) {
      const long long col = bcol + wc + n * 16 + l15;
      #pragma unroll
      for (int j = 0; j < 4; ++j) {
        const long long row = brow + wr + m * 16 + jhi * 4 + j;
        Cout[row * ldc + col] = acc[m][n][j];
      }
    }
  }
}

// ---------------- 256x256 8-wave, 4-slot rotation, reg-double-buffered frags --------
// K split across two segments (A0/B0 then A1/B1). EPI: *rowscale[row]*(1+vcol[col]).
template<int EPI>
__global__ __launch_bounds__(512, 2) void k_gemm256(
    const unsigned short* __restrict__ A0, int lda0,
    const unsigned short* __restrict__ A1, int lda1,
    const unsigned short* __restrict__ B0, int ldb0,
    const unsigned short* __restrict__ B1, int ldb1,
    int ka0, int Ktot, int gridM,
    float* __restrict__ Cout, int ldc,
    const float* __restrict__ rowscale, const float* __restrict__ vcol) {
  __shared__ unsigned short lds[4 * 16384];   // 128 KiB
  const int tid = threadIdx.x;
  const int lane = tid & 63;
  const int w = tid >> 6;            // 0..7
  const int wm = w >> 2;             // 0..1  (M half)
  const int wn = w & 3;              // 0..3  (N quarter)

  // bijective XCD swizzle (grid size divisible by 8)
  int bid = blockIdx.x;
  const int cpx = gridDim.x >> 3;
  bid = (bid & 7) * cpx + (bid >> 3);
  const int bx = bid % gridM;
  const int by = bid / gridM;
  const long long brow = (long long)bx * 256;
  const long long bcol = (long long)by * 256;

  const int c0 = w * 2;
  const int sr0 = lane >> 2;
  const int sj  = lane & 3;
  const int l15 = lane & 15;
  const int jhi = lane >> 4;

  auto stage = [&](int tt) {
    const int k0 = tt * 32;
    const unsigned short* PA; long long ldA; long long kA;
    const unsigned short* PB; long long ldB; long long kB;
    if (k0 < ka0) { PA = A0; ldA = lda0; kA = k0;       PB = B0; ldB = ldb0; kB = k0; }
    else          { PA = A1; ldA = lda1; kA = k0 - ka0; PB = B1; ldB = ldb1; kB = k0 - ka0; }
    unsigned short* dst = lds + (tt & 3) * 16384;
    #pragma unroll
    for (int c = 0; c < 2; ++c) {
      const int chunk = c0 + c;
      const int lrow = chunk * 16 + sr0;
      const int jj = sj ^ ((lrow >> 1) & 3);
      async_copy16(PA + (brow + lrow) * ldA + kA + jj * 8, (void*)(dst + chunk * 512));
      async_copy16(PB + (bcol + lrow) * ldB + kB + jj * 8, (void*)(dst + 8192 + chunk * 512));
    }
  };

  auto load_frags = [&](int tt, short8* av, short8* bv) {
    const unsigned short* Areg = lds + (tt & 3) * 16384;
    const unsigned short* Breg = Areg + 8192;
    #pragma unroll
    for (int m = 0; m < 8; ++m) {
      const int row = wm * 128 + m * 16 + l15;
      const int jj = jhi ^ ((row >> 1) & 3);
      av[m] = *(const short8*)(Areg + row * 32 + jj * 8);
    }
    #pragma unroll
    for (int n = 0; n < 4; ++n) {
      const int row = wn * 64 + n * 16 + l15;
      const int jj = jhi ^ ((row >> 1) & 3);
      bv[n] = *(const short8*)(Breg + row * 32 + jj * 8);
    }
  };

  f32x4 acc[8][4];
  #pragma unroll
  for (int m = 0; m < 8; ++m)
    #pragma unroll
    for (int n = 0; n < 4; ++n)
      #pragma unroll
      for (int j = 0; j < 4; ++j) acc[m][n][j] = 0.0f;

  auto do_mfma = [&](short8* av, short8* bv) {
    __builtin_amdgcn_s_setprio(1);
    #pragma unroll
    for (int m = 0; m < 8; ++m)
      #pragma unroll
      for (int n = 0; n < 4; ++n)
        acc[m][n] = __builtin_amdgcn_mfma_f32_16x16x32_bf16(av[m], bv[n], acc[m][n], 0, 0, 0);
    __builtin_amdgcn_s_setprio(0);
  };

  const int NT = Ktot >> 5;   // even (Ktot multiple of 64)
  stage(0); stage(1); stage(2);
  asm volatile("s_waitcnt vmcnt(4)" ::: "memory");   // tiles 0,1 landed
  __builtin_amdgcn_s_barrier();

  short8 avA[8], bvA[4], avB[8], bvB[4];
  load_frags(0, avA, bvA);

  for (int t = 0; t < NT; t += 2) {
    // body t: compute set A, read tile t+1 into set B
    if (t + 3 < NT) stage(t + 3);
    load_frags(t + 1, avB, bvB);
    do_mfma(avA, bvA);
    asm volatile("s_waitcnt vmcnt(4)" ::: "memory");
    __builtin_amdgcn_s_barrier();
    // body t+1: compute set B, read tile t+2 into set A
    if (t + 4 < NT) stage(t + 4);
    if (t + 2 < NT) load_frags(t + 2, avA, bvA);
    do_mfma(avB, bvB);
    asm volatile("s_waitcnt vmcnt(4)" ::: "memory");
    __builtin_amdgcn_s_barrier();
  }

  // epilogue: C/D layout col = lane&15, row = (lane>>4)*4 + j
  #pragma unroll
  for (int m = 0; m < 8; ++m) {
    #pragma unroll
    for (int n = 0; n < 4; ++n) {
      const long long col = bcol + wn * 64 + n * 16 + l15;
      float cs = 1.0f;
      if (EPI == 1) cs = 1.0f + vcol[col];
      #pragma unroll
      for (int j = 0; j < 4; ++j) {
        const long long row = brow + wm * 128 + m * 16 + jhi * 4 + j;
        float val = acc[m][n][j];
        if (EPI == 1) val *= rowscale[row] * cs;
        Cout[row * ldc + col] = val;
      }
    }
  }
}

extern "C" void kernel_launch(void* const* d_in, const int* in_sizes, int n_in,
                              void* d_out, int out_size, void* d_ws, size_t ws_size,
                              hipStream_t stream) {
  const float* x   = (const float*)d_in[0];
  const float* W   = (const float*)d_in[1];
  const float* U   = (const float*)d_in[2];
  const float* V   = (const float*)d_in[3];
  const float* lam = (const float*)d_in[4];
  const float* v   = (const float*)d_in[5];
  const float* Wg1 = (const float*)d_in[6];
  const float* Wg2 = (const float*)d_in[7];
  float* out = (float*)d_out;

  const int N = in_sizes[0] / D_DIM;        // 16384
  const int k = in_sizes[2] / D_DIM;        // SVD rank (~566)
  const int k_pad = (k + 127) & ~127;       // multiple of 128

  char* ws = (char*)d_ws;
  size_t off = 0;
  auto alloc = [&](size_t bytes) -> void* {
    void* p = ws + off;
    off += (bytes + 255) & ~(size_t)255;
    return p;
  };
  unsigned short* xb  = (unsigned short*)alloc((size_t)N * D_DIM * 2);
  unsigned short* Wt  = (unsigned short*)alloc((size_t)D_DIM * D_DIM * 2);
  unsigned short* Ukt = (unsigned short*)alloc((size_t)k_pad * D_DIM * 2);
  unsigned short* Vb  = (unsigned short*)alloc((size_t)D_DIM * k_pad * 2);
  float*          xu  = (float*)alloc((size_t)N * k_pad * 4);
  unsigned short* A2  = (unsigned short*)alloc((size_t)N * k_pad * 2);
  float*          rs  = (float*)alloc((size_t)N * 4);
  if (off > ws_size) return;

  // 1) conversions
  k_cvt_bf16<<<2048, 256, 0, stream>>>(x, xb, (long long)N * D_DIM);
  k_transpose_bf16<<<dim3(D_DIM / 32, D_DIM / 32), dim3(32, 8), 0, stream>>>(
      W, D_DIM, D_DIM, D_DIM, Wt, D_DIM);
  k_transpose_bf16<<<dim3(k_pad / 32, D_DIM / 32), dim3(32, 8), 0, stream>>>(
      U, D_DIM, k, k, Ukt, k_pad);
  k_pad_bf16<<<512, 256, 0, stream>>>(V, Vb, D_DIM, k, k_pad);

  // 2) xu = x @ U_k   [N, k_pad] f32
  k_gemm128<<<dim3(N / 128, k_pad / 128), 256, 0, stream>>>(
      xb, D_DIM, Ukt, D_DIM, D_DIM, xu, k_pad);

  // 3) routing -> A2, rowscale
  k_route<<<N / 4, 256, 0, stream>>>(xu, k, k_pad, Wg1, Wg2, lam, A2, rs, N);

  // 4) fused GEMM: out = (x@W + A2@V^T) * rowscale * (1+v)  [256^2 8-wave]
  const int gridM = N / 256;                 // 64
  const int gridN = D_DIM / 256;             // 8
  k_gemm256<1><<<gridM * gridN, 512, 0, stream>>>(
      xb, D_DIM, A2, k_pad,
      Wt, D_DIM, Vb, k_pad,
      D_DIM, D_DIM + k_pad, gridM,
      out, D_DIM, rs, v);
}